// Round 1
// baseline (398.808 us; speedup 1.0000x reference)
//
#include <hip/hip_runtime.h>
#include <math.h>

#define NF 16
#define EMB 32
#define W1K 7
#define W2K 5
#define VOCAB 100000
#define K1 8
#define K2 3

__global__ __launch_bounds__(256) void ccpm_fwd(
    const int* __restrict__ idx,
    const float* __restrict__ w0,
    const float* __restrict__ b0,
    const float* __restrict__ f1,
    const float* __restrict__ f2,
    const float* __restrict__ w1,
    const float* __restrict__ b1,
    float* __restrict__ out)
{
    const int b = blockIdx.x;
    const int t = threadIdx.x;

    __shared__ float tin[EMB][NF];           // tanh(emb), [e][f]
    __shared__ float c1[EMB][NF][2];         // conv1 out
    __shared__ float p1[EMB][K1][2];         // pool1 out
    __shared__ float c2[EMB][K1][2];         // conv2 out
    __shared__ float p2[EMB][K2][2];         // pool2 out
    __shared__ float sf1[EMB * W1K * 2];     // 448 filter1 [kh][kw][0][o]
    __shared__ float sf2[EMB * W2K * 2 * 2]; // 640 filter2 [kh][kw][i][o]
    __shared__ int   sidx[NF];
    __shared__ float red[256];

    // stage filters + indices
    for (int i = t; i < EMB * W1K * 2; i += 256) sf1[i] = f1[i];
    for (int i = t; i < EMB * W2K * 4; i += 256) sf2[i] = f2[i];
    if (t < NF) sidx[t] = idx[b * NF + t];
    __syncthreads();

    // embedding gather + bias + tanh, stored transposed [e][f]
    for (int n = t; n < NF * EMB; n += 256) {
        int f = n >> 5;
        int e = n & 31;
        long long row = (long long)f * VOCAB + sidx[f];
        float v = w0[row * EMB + e] + b0[f * EMB + e];
        tin[e][f] = tanhf(v);
    }
    __syncthreads();

    // conv1: SAME, kernel 32x7, input [32][16][1] -> out [32][16][2]
    // out[h][w][o] = sum_{kh,kw} tin[h+kh-15][w+kw-3] * f1[kh][kw][0][o]
    for (int n = t; n < EMB * NF * 2; n += 256) {
        int o = n & 1;
        int w = (n >> 1) & 15;
        int h = n >> 5;
        float acc = 0.f;
        int kh0 = max(0, 15 - h), kh1 = min(EMB - 1, 46 - h);
        int kw0 = max(0, 3 - w),  kw1 = min(W1K - 1, 18 - w);
        for (int kh = kh0; kh <= kh1; ++kh) {
            int hh = h + kh - 15;
            for (int kw = kw0; kw <= kw1; ++kw) {
                int ww = w + kw - 3;
                acc += tin[hh][ww] * sf1[(kh * W1K + kw) * 2 + o];
            }
        }
        c1[h][w][o] = acc;
    }
    __syncthreads();

    // pool1: per (e,o), top-8 of 16 values, descending
    if (t < EMB * 2) {
        int e = t >> 1, o = t & 1;
        float v[NF];
        for (int i = 0; i < NF; ++i) v[i] = c1[e][i][o];
        for (int j = 0; j < K1; ++j) {
            int mi = 0; float mv = v[0];
            for (int i = 1; i < NF; ++i) if (v[i] > mv) { mv = v[i]; mi = i; }
            p1[e][j][o] = mv;
            v[mi] = -INFINITY;
        }
    }
    __syncthreads();

    // conv2: SAME, kernel 32x5x2, input [32][8][2] -> out [32][8][2]
    for (int n = t; n < EMB * K1 * 2; n += 256) {
        int o = n & 1;
        int w = (n >> 1) & 7;
        int h = n >> 4;
        float acc = 0.f;
        int kh0 = max(0, 15 - h), kh1 = min(EMB - 1, 46 - h);
        int kw0 = max(0, 2 - w),  kw1 = min(W2K - 1, 9 - w);
        for (int kh = kh0; kh <= kh1; ++kh) {
            int hh = h + kh - 15;
            for (int kw = kw0; kw <= kw1; ++kw) {
                int ww = w + kw - 2;
                acc += p1[hh][ww][0] * sf2[(kh * W2K + kw) * 4 + 0 + o]
                     + p1[hh][ww][1] * sf2[(kh * W2K + kw) * 4 + 2 + o];
            }
        }
        c2[h][w][o] = acc;
    }
    __syncthreads();

    // pool2: per (e,o), top-3 of 8 values, descending
    if (t < EMB * 2) {
        int e = t >> 1, o = t & 1;
        float v[K1];
        for (int i = 0; i < K1; ++i) v[i] = c2[e][i][o];
        for (int j = 0; j < K2; ++j) {
            int mi = 0; float mv = v[0];
            for (int i = 1; i < K1; ++i) if (v[i] > mv) { mv = v[i]; mi = i; }
            p2[e][j][o] = mv;
            v[mi] = -INFINITY;
        }
    }
    __syncthreads();

    // final: tanh -> dot with w1[192] -> +b1 -> sigmoid
    float pv = 0.f;
    if (t < EMB * K2 * 2) {
        int e = t / 6;
        int r = t % 6;
        int j = r >> 1, o = r & 1;
        pv = tanhf(p2[e][j][o]) * w1[t];
    }
    red[t] = pv;
    __syncthreads();
    for (int s = 128; s > 0; s >>= 1) {
        if (t < s) red[t] += red[t + s];
        __syncthreads();
    }
    if (t == 0) {
        float logit = red[0] + b1[0];
        out[b] = 1.f / (1.f + expf(-logit));
    }
}

extern "C" void kernel_launch(void* const* d_in, const int* in_sizes, int n_in,
                              void* d_out, int out_size, void* d_ws, size_t ws_size,
                              hipStream_t stream) {
    const int*   idx = (const int*)d_in[0];
    const float* w0  = (const float*)d_in[1];
    const float* b0  = (const float*)d_in[2];
    const float* f1  = (const float*)d_in[3];
    const float* f2  = (const float*)d_in[4];
    const float* w1  = (const float*)d_in[5];
    const float* b1  = (const float*)d_in[6];
    float* out = (float*)d_out;
    ccpm_fwd<<<out_size, 256, 0, stream>>>(idx, w0, b0, f1, f2, w1, b1, out);
}

// Round 2
// 310.478 us; speedup vs baseline: 1.2845x; 1.2845x over previous
//
#include <hip/hip_runtime.h>
#include <math.h>

#define NF 16
#define EMB 32
#define VOCAB 100000
#define TS 28            // padded row stride (floats) for tin / p1p planes: 112 B spreads b128 bank groups
#define NROW 63          // padded H rows: hh in [-15, 47]
#define C1STR 36         // c1s row stride (floats), 144 B (16B-aligned, spreads banks)

__device__ __forceinline__ float tanhf_fast(float x) {
    float e = __expf(2.f * x);
    return 1.f - 2.f * __builtin_amdgcn_rcpf(e + 1.f);
}

__global__ __launch_bounds__(64) void ccpm_fwd(
    const int* __restrict__ idx,
    const float* __restrict__ w0,
    const float* __restrict__ b0,
    const float* __restrict__ f1,
    const float* __restrict__ f2,
    const float* __restrict__ w1,
    const float* __restrict__ b1,
    float* __restrict__ out)
{
    const int b = blockIdx.x;
    const int l = threadIdx.x;

    // buf: zero-padded input plane, reused for tin (conv1 in) then p1p (conv2 in)
    __shared__ float buf[NROW * TS];       // 63*28 = 1764 floats
    __shared__ float c1s[32 * C1STR];      // conv1 out [h][o*16+w]; aliased as conv2 out [h][o*8+w]
    float* c2s = c1s;

    const float4 z4 = make_float4(0.f, 0.f, 0.f, 0.f);

    // ---- phase 0: zero padded plane ----
    for (int i = l; i < (NROW * TS) / 4; i += 64) ((float4*)buf)[i] = z4;
    __syncthreads();

    // ---- phase 1: embedding gather + bias + tanh -> tin[e+15][f+3] ----
    {
        int f  = l >> 2;            // 0..15
        int e0 = (l & 3) * 8;       // 0,8,16,24
        int row = idx[b * NF + f];
        const float* src  = w0 + ((size_t)f * VOCAB + row) * EMB + e0;
        const float* bsrc = b0 + f * EMB + e0;
        float4 v0 = ((const float4*)src)[0];
        float4 v1 = ((const float4*)src)[1];
        float4 u0 = ((const float4*)bsrc)[0];
        float4 u1 = ((const float4*)bsrc)[1];
        float g[8];
        g[0]=v0.x+u0.x; g[1]=v0.y+u0.y; g[2]=v0.z+u0.z; g[3]=v0.w+u0.w;
        g[4]=v1.x+u1.x; g[5]=v1.y+u1.y; g[6]=v1.z+u1.z; g[7]=v1.w+u1.w;
        #pragma unroll
        for (int i = 0; i < 8; ++i)
            buf[(e0 + i + 15) * TS + f + 3] = tanhf_fast(g[i]);
    }
    __syncthreads();

    const int h  = l >> 1;          // 0..31
    const int wh = l & 1;

    // ---- phase 2: conv1 (32x7 SAME) -> c1s[h][o*16+w] ----
    {
        const int wb = wh * 8;
        float a0[8], a1[8];
        #pragma unroll
        for (int w = 0; w < 8; ++w) { a0[w] = 0.f; a1[w] = 0.f; }
        const float2* f1v = (const float2*)f1;   // [kh*7+kw] -> {o0,o1}
        for (int kh = 0; kh < 32; ++kh) {
            const float* r = &buf[(h + kh) * TS + wb];
            float4 q0 = ((const float4*)r)[0];
            float4 q1 = ((const float4*)r)[1];
            float4 q2 = ((const float4*)r)[2];
            float4 q3 = ((const float4*)r)[3];
            float win[16];
            win[0]=q0.x; win[1]=q0.y; win[2]=q0.z; win[3]=q0.w;
            win[4]=q1.x; win[5]=q1.y; win[6]=q1.z; win[7]=q1.w;
            win[8]=q2.x; win[9]=q2.y; win[10]=q2.z; win[11]=q2.w;
            win[12]=q3.x; win[13]=q3.y; win[14]=q3.z; win[15]=q3.w;
            #pragma unroll
            for (int kw = 0; kw < 7; ++kw) {
                float2 fp = f1v[kh * 7 + kw];    // uniform -> s_load
                #pragma unroll
                for (int w = 0; w < 8; ++w) {
                    a0[w] += win[w + kw] * fp.x;
                    a1[w] += win[w + kw] * fp.y;
                }
            }
        }
        float* crow = &c1s[h * C1STR + wb];
        ((float4*)crow)[0] = make_float4(a0[0], a0[1], a0[2], a0[3]);
        ((float4*)crow)[1] = make_float4(a0[4], a0[5], a0[6], a0[7]);
        ((float4*)(crow + 16))[0] = make_float4(a1[0], a1[1], a1[2], a1[3]);
        ((float4*)(crow + 16))[1] = make_float4(a1[4], a1[5], a1[6], a1[7]);
    }
    __syncthreads();

    // ---- phase 3: re-zero plane for conv2 input ----
    for (int i = l; i < (NROW * TS) / 4; i += 64) ((float4*)buf)[i] = z4;
    __syncthreads();

    // ---- phase 4: pool1: per (e,o) top-8 of 16 (desc) -> p1p[e+15][o*12 + j+2] ----
    {
        int e = h, o = wh;
        const float* row = &c1s[e * C1STR + o * 16];
        float4 q0 = ((const float4*)row)[0];
        float4 q1 = ((const float4*)row)[1];
        float4 q2 = ((const float4*)row)[2];
        float4 q3 = ((const float4*)row)[3];
        float v[16];
        v[0]=q0.x; v[1]=q0.y; v[2]=q0.z; v[3]=q0.w;
        v[4]=q1.x; v[5]=q1.y; v[6]=q1.z; v[7]=q1.w;
        v[8]=q2.x; v[9]=q2.y; v[10]=q2.z; v[11]=q2.w;
        v[12]=q3.x; v[13]=q3.y; v[14]=q3.z; v[15]=q3.w;
        #pragma unroll
        for (int i = 0; i < 16; ++i) {
            int r = 0;
            #pragma unroll
            for (int j = 0; j < 16; ++j) {
                if (j == i) continue;
                r += ((v[j] > v[i]) || (v[j] == v[i] && j < i)) ? 1 : 0;
            }
            if (r < 8) buf[(e + 15) * TS + o * 12 + 2 + r] = v[i];
        }
    }
    __syncthreads();

    // ---- phase 5: conv2 (32x5x2 SAME) -> c2s[h][o*8+w] ----
    {
        const int wb = wh * 4;
        float a0[4], a1[4];
        #pragma unroll
        for (int w = 0; w < 4; ++w) { a0[w] = 0.f; a1[w] = 0.f; }
        const float4* f2q = (const float4*)f2;   // [kh*5+kw] -> {i0o0,i0o1,i1o0,i1o1}
        for (int kh = 0; kh < 32; ++kh) {
            const float* r = &buf[(h + kh) * TS];
            float4 p0a = ((const float4*)(r + wb))[0];
            float4 p0b = ((const float4*)(r + wb))[1];
            float4 p1a = ((const float4*)(r + 12 + wb))[0];
            float4 p1b = ((const float4*)(r + 12 + wb))[1];
            float q0[8], q1[8];
            q0[0]=p0a.x; q0[1]=p0a.y; q0[2]=p0a.z; q0[3]=p0a.w;
            q0[4]=p0b.x; q0[5]=p0b.y; q0[6]=p0b.z; q0[7]=p0b.w;
            q1[0]=p1a.x; q1[1]=p1a.y; q1[2]=p1a.z; q1[3]=p1a.w;
            q1[4]=p1b.x; q1[5]=p1b.y; q1[6]=p1b.z; q1[7]=p1b.w;
            #pragma unroll
            for (int kw = 0; kw < 5; ++kw) {
                float4 fp = f2q[kh * 5 + kw];    // uniform -> s_load
                #pragma unroll
                for (int w = 0; w < 4; ++w) {
                    a0[w] += q0[w + kw] * fp.x + q1[w + kw] * fp.z;
                    a1[w] += q0[w + kw] * fp.y + q1[w + kw] * fp.w;
                }
            }
        }
        float* crow = &c2s[h * 16 + wb];
        ((float4*)crow)[0]       = make_float4(a0[0], a0[1], a0[2], a0[3]);
        ((float4*)(crow + 8))[0] = make_float4(a1[0], a1[1], a1[2], a1[3]);
    }
    __syncthreads();

    // ---- phase 6: pool2 top-3 of 8 (desc) + tanh + dot(w1) + sigmoid ----
    {
        int e = h, o = wh;
        const float* row = &c2s[e * 16 + o * 8];
        float4 qa = ((const float4*)row)[0];
        float4 qb = ((const float4*)row)[1];
        float v[8];
        v[0]=qa.x; v[1]=qa.y; v[2]=qa.z; v[3]=qa.w;
        v[4]=qb.x; v[5]=qb.y; v[6]=qb.z; v[7]=qb.w;
        float t0 = 0.f, t1 = 0.f, t2 = 0.f;
        #pragma unroll
        for (int i = 0; i < 8; ++i) {
            int r = 0;
            #pragma unroll
            for (int j = 0; j < 8; ++j) {
                if (j == i) continue;
                r += ((v[j] > v[i]) || (v[j] == v[i] && j < i)) ? 1 : 0;
            }
            t0 = (r == 0) ? v[i] : t0;
            t1 = (r == 1) ? v[i] : t1;
            t2 = (r == 2) ? v[i] : t2;
        }
        float s = tanhf_fast(t0) * w1[e * 6 + o]
                + tanhf_fast(t1) * w1[e * 6 + 2 + o]
                + tanhf_fast(t2) * w1[e * 6 + 4 + o];
        #pragma unroll
        for (int off = 32; off; off >>= 1) s += __shfl_xor(s, off, 64);
        if (l == 0) {
            float logit = s + b1[0];
            out[b] = __builtin_amdgcn_rcpf(1.f + __expf(-logit));
        }
    }
}

extern "C" void kernel_launch(void* const* d_in, const int* in_sizes, int n_in,
                              void* d_out, int out_size, void* d_ws, size_t ws_size,
                              hipStream_t stream) {
    const int*   idx = (const int*)d_in[0];
    const float* w0  = (const float*)d_in[1];
    const float* b0  = (const float*)d_in[2];
    const float* f1  = (const float*)d_in[3];
    const float* f2  = (const float*)d_in[4];
    const float* w1  = (const float*)d_in[5];
    const float* b1  = (const float*)d_in[6];
    float* out = (float*)d_out;
    ccpm_fwd<<<out_size, 64, 0, stream>>>(idx, w0, b0, f1, f2, w1, b1, out);
}

// Round 3
// 294.429 us; speedup vs baseline: 1.3545x; 1.0545x over previous
//
#include <hip/hip_runtime.h>
#include <math.h>

#define NF 16
#define VOCAB 100000
#define TSH 40          // halves per padded row (80 B: 16B-aligned, start banks spread)
#define NROW 63         // rows: hh in [-15, 47]

typedef _Float16 half8 __attribute__((ext_vector_type(8)));
typedef _Float16 half4 __attribute__((ext_vector_type(4)));

__device__ __forceinline__ float tanhf_fast(float x) {
    float e = __expf(2.f * x);
    return 1.f - 2.f * __builtin_amdgcn_rcpf(e + 1.f);
}

__global__ __launch_bounds__(64, 6) void ccpm_fwd(
    const int* __restrict__ idx,
    const float* __restrict__ w0,
    const float* __restrict__ b0,
    const float* __restrict__ f1,
    const float* __restrict__ f2,
    const float* __restrict__ w1,
    const float* __restrict__ b1,
    float* __restrict__ out)
{
    const int b = blockIdx.x;
    const int l = threadIdx.x;

    // single zero-padded fp16 plane, reused for conv1-in (tanh emb) then conv2-in (pool1 out)
    __shared__ __align__(16) _Float16 buf[NROW * TSH + 8];   // 2528 halves = 5056 B

    const float4 z4 = make_float4(0.f, 0.f, 0.f, 0.f);
    float4* bz = (float4*)buf;

    // ---- phase 0: zero plane ----
    #pragma unroll
    for (int i = 0; i < 5; ++i) {
        int n = i * 64 + l;
        if (n < (NROW * TSH + 8) / 8) bz[n] = z4;
    }
    __syncthreads();

    // ---- phase 1: embedding gather + bias + tanh -> plane[e+15][f+3] (fp16) ----
    {
        int f  = l >> 2;            // 0..15
        int e0 = (l & 3) * 8;       // 0,8,16,24
        int row = idx[b * NF + f];
        const float4* src = (const float4*)(w0 + ((size_t)f * VOCAB + row) * 32 + e0);
        const float4* bb  = (const float4*)(b0 + f * 32 + e0);
        float4 v0 = src[0], v1 = src[1];
        float4 u0 = bb[0],  u1 = bb[1];
        float g[8];
        g[0]=v0.x+u0.x; g[1]=v0.y+u0.y; g[2]=v0.z+u0.z; g[3]=v0.w+u0.w;
        g[4]=v1.x+u1.x; g[5]=v1.y+u1.y; g[6]=v1.z+u1.z; g[7]=v1.w+u1.w;
        #pragma unroll
        for (int i = 0; i < 8; ++i)
            buf[(e0 + i + 15) * TSH + f + 3] = (_Float16)tanhf_fast(g[i]);
    }
    __syncthreads();

    const int h  = l >> 1;          // 0..31  (output row e)
    const int wh = l & 1;           // half / output channel for pooling

    // ---- phase 2: conv1 (32x7 SAME) -> registers a0[8] (o=0), a1[8] (o=1) for w in [8*wh, 8*wh+8) ----
    float a0[8], a1[8];
    {
        #pragma unroll
        for (int w = 0; w < 8; ++w) { a0[w] = 0.f; a1[w] = 0.f; }
        const float2* f1v = (const float2*)f1;   // [kh*7+kw] -> {o0,o1}, wave-uniform -> s_load
        #pragma unroll 2
        for (int kh = 0; kh < 32; ++kh) {
            const half8* r = (const half8*)&buf[(h + kh) * TSH + 8 * wh];
            half8 wa = r[0];
            half8 wbv = r[1];
            float win[16];
            #pragma unroll
            for (int i = 0; i < 8; ++i) { win[i] = (float)wa[i]; win[8 + i] = (float)wbv[i]; }
            #pragma unroll
            for (int kw = 0; kw < 7; ++kw) {
                float2 fp = f1v[kh * 7 + kw];
                #pragma unroll
                for (int w = 0; w < 8; ++w) {
                    a0[w] += win[w + kw] * fp.x;
                    a1[w] += win[w + kw] * fp.y;
                }
            }
        }
    }
    __syncthreads();           // conv1 reads of plane complete

    // ---- phase 3: re-zero plane ----
    #pragma unroll
    for (int i = 0; i < 5; ++i) {
        int n = i * 64 + l;
        if (n < (NROW * TSH + 8) / 8) bz[n] = z4;
    }
    __syncthreads();

    // ---- phase 4: pool1 top-8 of 16 (desc). lane (2e+o) pools (e=h, o=wh).
    //      partner exchange: own half-row + partner half-row via shfl_xor(1). ----
    {
        float own[8], recv[8];
        #pragma unroll
        for (int i = 0; i < 8; ++i) {
            own[i]  = wh ? a1[i] : a0[i];                  // own w-range, channel o=wh
            recv[i] = __shfl_xor(wh ? a0[i] : a1[i], 1, 64); // partner's w-range, channel o=wh
        }
        float v[16];
        #pragma unroll
        for (int i = 0; i < 8; ++i) {
            v[i]     = wh ? recv[i] : own[i];              // w 0..7
            v[8 + i] = wh ? own[i] : recv[i];              // w 8..15
        }
        int r[16];
        #pragma unroll
        for (int i = 0; i < 16; ++i) r[i] = 0;
        #pragma unroll
        for (int i = 0; i < 16; ++i)
            #pragma unroll
            for (int j = i + 1; j < 16; ++j) {
                bool ge = v[i] >= v[j];                    // tie -> earlier index wins
                r[j] += ge ? 1 : 0;
                r[i] += ge ? 0 : 1;
            }
        #pragma unroll
        for (int i = 0; i < 16; ++i)
            if (r[i] < 8) buf[(h + 15) * TSH + wh * 12 + 2 + r[i]] = (_Float16)v[i];
    }
    __syncthreads();

    // ---- phase 5: conv2 (32x5x2 SAME) -> registers c0[4], c1[4] for w in [4*wh, 4*wh+4) ----
    float c0[4], c1[4];
    {
        #pragma unroll
        for (int w = 0; w < 4; ++w) { c0[w] = 0.f; c1[w] = 0.f; }
        const float4* f2q = (const float4*)f2;   // [kh*5+kw] -> {i0o0,i0o1,i1o0,i1o1}, uniform
        #pragma unroll 2
        for (int kh = 0; kh < 32; ++kh) {
            const _Float16* rw = &buf[(h + kh) * TSH];
            half4 p0a = *(const half4*)(rw + 4 * wh);
            half4 p0b = *(const half4*)(rw + 4 * wh + 4);
            half4 p1a = *(const half4*)(rw + 12 + 4 * wh);
            half4 p1b = *(const half4*)(rw + 16 + 4 * wh);
            float q0[8], q1[8];
            #pragma unroll
            for (int i = 0; i < 4; ++i) {
                q0[i] = (float)p0a[i]; q0[4 + i] = (float)p0b[i];
                q1[i] = (float)p1a[i]; q1[4 + i] = (float)p1b[i];
            }
            #pragma unroll
            for (int kw = 0; kw < 5; ++kw) {
                float4 fp = f2q[kh * 5 + kw];
                #pragma unroll
                for (int w = 0; w < 4; ++w) {
                    c0[w] += q0[w + kw] * fp.x + q1[w + kw] * fp.z;
                    c1[w] += q0[w + kw] * fp.y + q1[w + kw] * fp.w;
                }
            }
        }
    }

    // ---- phase 6: pool2 top-3 of 8 + tanh + dot(w1) + sigmoid (all in registers) ----
    {
        float own[4], recv[4];
        #pragma unroll
        for (int i = 0; i < 4; ++i) {
            own[i]  = wh ? c1[i] : c0[i];
            recv[i] = __shfl_xor(wh ? c0[i] : c1[i], 1, 64);
        }
        float v[8];
        #pragma unroll
        for (int i = 0; i < 4; ++i) {
            v[i]     = wh ? recv[i] : own[i];
            v[4 + i] = wh ? own[i] : recv[i];
        }
        int r[8];
        #pragma unroll
        for (int i = 0; i < 8; ++i) r[i] = 0;
        #pragma unroll
        for (int i = 0; i < 8; ++i)
            #pragma unroll
            for (int j = i + 1; j < 8; ++j) {
                bool ge = v[i] >= v[j];
                r[j] += ge ? 1 : 0;
                r[i] += ge ? 0 : 1;
            }
        float t0 = 0.f, t1 = 0.f, t2 = 0.f;
        #pragma unroll
        for (int i = 0; i < 8; ++i) {
            t0 = (r[i] == 0) ? v[i] : t0;
            t1 = (r[i] == 1) ? v[i] : t1;
            t2 = (r[i] == 2) ? v[i] : t2;
        }
        float s = tanhf_fast(t0) * w1[h * 6 + wh]
                + tanhf_fast(t1) * w1[h * 6 + 2 + wh]
                + tanhf_fast(t2) * w1[h * 6 + 4 + wh];
        #pragma unroll
        for (int off = 32; off; off >>= 1) s += __shfl_xor(s, off, 64);
        if (l == 0) {
            float logit = s + b1[0];
            out[b] = __builtin_amdgcn_rcpf(1.f + __expf(-logit));
        }
    }
}

extern "C" void kernel_launch(void* const* d_in, const int* in_sizes, int n_in,
                              void* d_out, int out_size, void* d_ws, size_t ws_size,
                              hipStream_t stream) {
    const int*   idx = (const int*)d_in[0];
    const float* w0  = (const float*)d_in[1];
    const float* b0  = (const float*)d_in[2];
    const float* f1  = (const float*)d_in[3];
    const float* f2  = (const float*)d_in[4];
    const float* w1  = (const float*)d_in[5];
    const float* b1  = (const float*)d_in[6];
    float* out = (float*)d_out;
    ccpm_fwd<<<out_size, 64, 0, stream>>>(idx, w0, b0, f1, f2, w1, b1, out);
}

// Round 4
// 279.076 us; speedup vs baseline: 1.4290x; 1.0550x over previous
//
#include <hip/hip_runtime.h>
#include <math.h>

#define NF 16
#define VOCAB 100000
#define S1 28      // conv1 plane stride, dwords per pair-row (112 B)
#define NP1 31     // pair-rows per conv1 plane
#define PB 868     // plane B base (dwords) = NP1*S1
#define S2 20      // conv2 plane stride, dwords per row (80 B)
#define LDSW 1736  // total LDS dwords (= 2 conv1 planes; conv2 plane aliases onto it)

typedef _Float16 h2 __attribute__((ext_vector_type(2)));

#if __has_builtin(__builtin_amdgcn_fdot2)
#define FDOT2(a, b, c) __builtin_amdgcn_fdot2((a), (b), (c), false)
#else
#define FDOT2(a, b, c) ((float)(a)[0] * (float)(b)[0] + ((float)(a)[1] * (float)(b)[1] + (c)))
#endif

__device__ __forceinline__ float tanhf_fast(float x) {
    float e = __expf(2.f * x);
    return 1.f - 2.f * __builtin_amdgcn_rcpf(e + 1.f);
}

__device__ __forceinline__ h2 u2h(unsigned int u) {
    union { unsigned int u; h2 h; } c; c.u = u; return c.h;
}

// Packs filter tables (fp16 pairs) into ws each launch.
// ws[0..223]   : F1P[j][kw][o] = {f1[2j][kw][o], f1[2j+1][kw][o]}      (j=0..15)
// ws[256..575] : F2P[kh][kw][o] = {f2[kh][kw][0][o], f2[kh][kw][1][o]} (kh=0..31)
__global__ void pack_filters(const float* __restrict__ f1,
                             const float* __restrict__ f2,
                             unsigned int* __restrict__ ws) {
    int t = threadIdx.x;
    if (t < 224) {
        int j = t / 14, r = t % 14, kw = r >> 1, o = r & 1;
        h2 h;
        h[0] = (_Float16)f1[((2 * j) * 7 + kw) * 2 + o];
        h[1] = (_Float16)f1[((2 * j + 1) * 7 + kw) * 2 + o];
        union { h2 h; unsigned int u; } c; c.h = h;
        ws[t] = c.u;
    }
    for (int n = t; n < 320; n += 256) {
        int kh = n / 10, r = n % 10, kw = r >> 1, o = r & 1;
        h2 h;
        h[0] = (_Float16)f2[(kh * 5 + kw) * 4 + o];
        h[1] = (_Float16)f2[(kh * 5 + kw) * 4 + 2 + o];
        union { h2 h; unsigned int u; } c; c.h = h;
        ws[256 + n] = c.u;
    }
}

__global__ __launch_bounds__(64, 4) void ccpm_fwd(
    const int* __restrict__ idx,
    const float* __restrict__ w0,
    const float* __restrict__ b0,
    const float* __restrict__ w1,
    const float* __restrict__ b1,
    const unsigned int* __restrict__ FP,   // ws: F1P at 0, F2P at 256
    float* __restrict__ out)
{
    const int b = blockIdx.x;
    const int l = threadIdx.x;

    __shared__ __align__(16) unsigned int lds[LDSW];

    const float4 z4 = make_float4(0.f, 0.f, 0.f, 0.f);

    // ---- phase 0: zero both conv1 planes ----
    #pragma unroll
    for (int i = 0; i < 7; ++i) {
        int n = i * 64 + l;
        if (n < LDSW / 4) ((float4*)lds)[n] = z4;
    }
    __syncthreads();

    // ---- phase 1: embedding gather + bias + tanh -> both row-interleaved planes ----
    {
        int f  = l >> 2;            // 0..15
        int e0 = (l & 3) * 8;       // 0,8,16,24
        int row = idx[b * NF + f];
        const float4* src = (const float4*)(w0 + ((size_t)f * VOCAB + row) * 32 + e0);
        const float4* bb  = (const float4*)(b0 + f * 32 + e0);
        float4 v0 = src[0], v1 = src[1];
        float4 u0 = bb[0],  u1 = bb[1];
        float g[8];
        g[0]=v0.x+u0.x; g[1]=v0.y+u0.y; g[2]=v0.z+u0.z; g[3]=v0.w+u0.w;
        g[4]=v1.x+u1.x; g[5]=v1.y+u1.y; g[6]=v1.z+u1.z; g[7]=v1.w+u1.w;
        _Float16* H = (_Float16*)lds;
        const int C = f + 3;
        #pragma unroll
        for (int i = 0; i < 8; ++i) {
            int R = e0 + i + 15;                 // padded row, 15..46
            _Float16 hv = (_Float16)tanhf_fast(g[i]);
            // plane A: dword (R>>1, C) holds rows (2pr, 2pr+1)
            H[((R >> 1) * S1 + C) * 2 + (R & 1)] = hv;
            // plane B: dword (pr, C) holds rows (2pr+1, 2pr+2)
            int prB = (R & 1) ? (R >> 1) : (R >> 1) - 1;
            H[(PB + prB * S1 + C) * 2 + ((R & 1) ^ 1)] = hv;
        }
    }
    __syncthreads();

    const int h  = l >> 1;          // output row e, 0..31
    const int wh = l & 1;

    // ---- phase 2: conv1 (32x7 SAME), kh-paired dot2 ----
    float a0[8], a1[8];
    {
        #pragma unroll
        for (int w = 0; w < 8; ++w) { a0[w] = 0.f; a1[w] = 0.f; }
        const unsigned int* plane = lds + ((h & 1) ? PB : 0);
        const int pr0 = h >> 1;
        const int wb  = wh * 8;
        #pragma unroll 2
        for (int j = 0; j < 16; ++j) {           // kh pair (2j, 2j+1)
            const uint4* rp = (const uint4*)(plane + (pr0 + j) * S1 + wb);
            uint4 q0 = rp[0], q1 = rp[1], q2 = rp[2], q3 = rp[3];
            unsigned int win[16] = {q0.x,q0.y,q0.z,q0.w, q1.x,q1.y,q1.z,q1.w,
                                    q2.x,q2.y,q2.z,q2.w, q3.x,q3.y,q3.z,q3.w};
            const unsigned int* ft = FP + j * 14;  // wave-uniform -> s_load
            #pragma unroll
            for (int kw = 0; kw < 7; ++kw) {
                h2 f0 = u2h(ft[kw * 2 + 0]);
                h2 f1h = u2h(ft[kw * 2 + 1]);
                #pragma unroll
                for (int w = 0; w < 8; ++w) {
                    h2 wv = u2h(win[w + kw]);
                    a0[w] = FDOT2(wv, f0, a0[w]);
                    a1[w] = FDOT2(wv, f1h, a1[w]);
                }
            }
        }
    }
    __syncthreads();

    // ---- phase 3: re-zero conv2 plane region (63 rows x S2 dwords) ----
    #pragma unroll
    for (int i = 0; i < 5; ++i) {
        int n = i * 64 + l;
        if (n < (63 * S2) / 4) ((float4*)lds)[n] = z4;
    }
    __syncthreads();

    // ---- phase 4: pool1 top-8 of 16 -> conv2 plane, i-channels packed per dword ----
    {
        float own[8], recv[8];
        #pragma unroll
        for (int i = 0; i < 8; ++i) {
            own[i]  = wh ? a1[i] : a0[i];
            recv[i] = __shfl_xor(wh ? a0[i] : a1[i], 1, 64);
        }
        float v[16];
        #pragma unroll
        for (int i = 0; i < 8; ++i) {
            v[i]     = wh ? recv[i] : own[i];
            v[8 + i] = wh ? own[i] : recv[i];
        }
        int r[16];
        #pragma unroll
        for (int i = 0; i < 16; ++i) r[i] = 0;
        #pragma unroll
        for (int i = 0; i < 16; ++i)
            #pragma unroll
            for (int j = i + 1; j < 16; ++j) {
                bool ge = v[i] >= v[j];          // tie -> earlier index wins
                r[j] += ge ? 1 : 0;
                r[i] += ge ? 0 : 1;
            }
        _Float16* H = (_Float16*)lds;
        #pragma unroll
        for (int i = 0; i < 16; ++i)
            if (r[i] < 8)
                H[((h + 15) * S2 + (r[i] + 2)) * 2 + wh] = (_Float16)v[i];
    }
    __syncthreads();

    // ---- phase 5: conv2 (32x5x2 SAME), i-paired dot2 ----
    float c0[4], c1[4];
    {
        #pragma unroll
        for (int w = 0; w < 4; ++w) { c0[w] = 0.f; c1[w] = 0.f; }
        const int wb2 = wh * 4;
        #pragma unroll 2
        for (int kh = 0; kh < 32; ++kh) {
            const uint4* rp = (const uint4*)(lds + (h + kh) * S2 + wb2);
            uint4 qa = rp[0], qb = rp[1];
            unsigned int q[8] = {qa.x,qa.y,qa.z,qa.w, qb.x,qb.y,qb.z,qb.w};
            const unsigned int* ft = FP + 256 + kh * 10;  // uniform -> s_load
            #pragma unroll
            for (int kw = 0; kw < 5; ++kw) {
                h2 f0 = u2h(ft[kw * 2 + 0]);
                h2 f1h = u2h(ft[kw * 2 + 1]);
                #pragma unroll
                for (int w = 0; w < 4; ++w) {
                    h2 wv = u2h(q[w + kw]);
                    c0[w] = FDOT2(wv, f0, c0[w]);
                    c1[w] = FDOT2(wv, f1h, c1[w]);
                }
            }
        }
    }

    // ---- phase 6: pool2 top-3 of 8 + tanh + dot(w1) + sigmoid ----
    {
        float own[4], recv[4];
        #pragma unroll
        for (int i = 0; i < 4; ++i) {
            own[i]  = wh ? c1[i] : c0[i];
            recv[i] = __shfl_xor(wh ? c0[i] : c1[i], 1, 64);
        }
        float v[8];
        #pragma unroll
        for (int i = 0; i < 4; ++i) {
            v[i]     = wh ? recv[i] : own[i];
            v[4 + i] = wh ? own[i] : recv[i];
        }
        int r[8];
        #pragma unroll
        for (int i = 0; i < 8; ++i) r[i] = 0;
        #pragma unroll
        for (int i = 0; i < 8; ++i)
            #pragma unroll
            for (int j = i + 1; j < 8; ++j) {
                bool ge = v[i] >= v[j];
                r[j] += ge ? 1 : 0;
                r[i] += ge ? 0 : 1;
            }
        float t0 = 0.f, t1 = 0.f, t2 = 0.f;
        #pragma unroll
        for (int i = 0; i < 8; ++i) {
            t0 = (r[i] == 0) ? v[i] : t0;
            t1 = (r[i] == 1) ? v[i] : t1;
            t2 = (r[i] == 2) ? v[i] : t2;
        }
        float s = tanhf_fast(t0) * w1[h * 6 + wh]
                + tanhf_fast(t1) * w1[h * 6 + 2 + wh]
                + tanhf_fast(t2) * w1[h * 6 + 4 + wh];
        #pragma unroll
        for (int off = 32; off; off >>= 1) s += __shfl_xor(s, off, 64);
        if (l == 0) {
            float logit = s + b1[0];
            out[b] = __builtin_amdgcn_rcpf(1.f + __expf(-logit));
        }
    }
}

extern "C" void kernel_launch(void* const* d_in, const int* in_sizes, int n_in,
                              void* d_out, int out_size, void* d_ws, size_t ws_size,
                              hipStream_t stream) {
    const int*   idx = (const int*)d_in[0];
    const float* w0  = (const float*)d_in[1];
    const float* b0  = (const float*)d_in[2];
    const float* f1  = (const float*)d_in[3];
    const float* f2  = (const float*)d_in[4];
    const float* w1  = (const float*)d_in[5];
    const float* b1  = (const float*)d_in[6];
    float* out = (float*)d_out;
    unsigned int* ws = (unsigned int*)d_ws;

    pack_filters<<<1, 256, 0, stream>>>(f1, f2, ws);
    ccpm_fwd<<<out_size, 64, 0, stream>>>(idx, w0, b0, w1, b1, ws, out);
}

// Round 5
// 279.035 us; speedup vs baseline: 1.4292x; 1.0001x over previous
//
#include <hip/hip_runtime.h>
#include <math.h>

#define NF 16
#define VOCAB 100000
#define S1 28      // conv1 plane stride, dwords per pair-row (112 B)
#define NP1 31     // pair-rows per conv1 plane
#define PB 868     // plane B base (dwords) = NP1*S1
#define S2 20      // conv2 plane stride, dwords per row (80 B)
#define F1B 1736   // filter1 LDS base (dwords), 16B aligned
#define F2B 1992   // filter2 LDS base (dwords), 16B aligned
#define LDSW 2376  // total LDS dwords

typedef _Float16 h2 __attribute__((ext_vector_type(2)));

#if __has_builtin(__builtin_amdgcn_fdot2)
#define FDOT2(a, b, c) __builtin_amdgcn_fdot2((a), (b), (c), false)
#else
#define FDOT2(a, b, c) ((float)(a)[0] * (float)(b)[0] + ((float)(a)[1] * (float)(b)[1] + (c)))
#endif

__device__ __forceinline__ float tanhf_fast(float x) {
    float e = __expf(2.f * x);
    return 1.f - 2.f * __builtin_amdgcn_rcpf(e + 1.f);
}

__device__ __forceinline__ h2 u2h(unsigned int u) {
    union { unsigned int u; h2 h; } c; c.u = u; return c.h;
}

// Packs filter tables (fp16 pairs) into ws each launch, padded strides:
// ws[j*16 + kw*2 + o]        = {f1[2j][kw][o], f1[2j+1][kw][o]}       j<16 (rows of 16, 14 used)
// ws[256 + kh*12 + kw*2 + o] = {f2[kh][kw][0][o], f2[kh][kw][1][o]}   kh<32 (rows of 12, 10 used)
__global__ void pack_filters(const float* __restrict__ f1,
                             const float* __restrict__ f2,
                             unsigned int* __restrict__ ws) {
    int t = threadIdx.x;
    if (t < 224) {
        int j = t / 14, r = t % 14, kw = r >> 1, o = r & 1;
        h2 h;
        h[0] = (_Float16)f1[((2 * j) * 7 + kw) * 2 + o];
        h[1] = (_Float16)f1[((2 * j + 1) * 7 + kw) * 2 + o];
        union { h2 h; unsigned int u; } c; c.h = h;
        ws[j * 16 + r] = c.u;
    }
    for (int n = t; n < 320; n += 256) {
        int kh = n / 10, r = n % 10, kw = r >> 1, o = r & 1;
        h2 h;
        h[0] = (_Float16)f2[(kh * 5 + kw) * 4 + o];
        h[1] = (_Float16)f2[(kh * 5 + kw) * 4 + 2 + o];
        union { h2 h; unsigned int u; } c; c.h = h;
        ws[256 + kh * 12 + r] = c.u;
    }
}

__global__ __launch_bounds__(64, 4) void ccpm_fwd(
    const int* __restrict__ idx,
    const float* __restrict__ w0,
    const float* __restrict__ b0,
    const float* __restrict__ w1,
    const float* __restrict__ b1,
    const unsigned int* __restrict__ FP,   // ws: F1 at 0 (256 dw), F2 at 256 (384 dw)
    float* __restrict__ out)
{
    const int b = blockIdx.x;
    const int l = threadIdx.x;

    __shared__ __align__(16) unsigned int lds[LDSW];

    const float4 z4 = make_float4(0.f, 0.f, 0.f, 0.f);

    // ---- phase 0a: stage filter tables global -> LDS (640 dwords = 5 x 64 x uint2) ----
    {
        const uint2* src = (const uint2*)FP;
        uint2* dst = (uint2*)(lds + F1B);
        #pragma unroll
        for (int i = 0; i < 5; ++i) dst[i * 64 + l] = src[i * 64 + l];
    }
    // ---- phase 0b: zero both conv1 planes ----
    #pragma unroll
    for (int i = 0; i < 7; ++i) {
        int n = i * 64 + l;
        if (n < F1B / 4) ((float4*)lds)[n] = z4;
    }
    __syncthreads();

    // ---- phase 1: embedding gather + bias + tanh -> both row-interleaved planes ----
    {
        int f  = l >> 2;            // 0..15
        int e0 = (l & 3) * 8;       // 0,8,16,24
        int row = idx[b * NF + f];
        const float4* src = (const float4*)(w0 + ((size_t)f * VOCAB + row) * 32 + e0);
        const float4* bb  = (const float4*)(b0 + f * 32 + e0);
        float4 v0 = src[0], v1 = src[1];
        float4 u0 = bb[0],  u1 = bb[1];
        float g[8];
        g[0]=v0.x+u0.x; g[1]=v0.y+u0.y; g[2]=v0.z+u0.z; g[3]=v0.w+u0.w;
        g[4]=v1.x+u1.x; g[5]=v1.y+u1.y; g[6]=v1.z+u1.z; g[7]=v1.w+u1.w;
        _Float16* H = (_Float16*)lds;
        const int C = f + 3;
        #pragma unroll
        for (int i = 0; i < 8; ++i) {
            int R = e0 + i + 15;                 // padded row, 15..46
            _Float16 hv = (_Float16)tanhf_fast(g[i]);
            H[((R >> 1) * S1 + C) * 2 + (R & 1)] = hv;          // plane A (rows 2pr,2pr+1)
            int prB = (R & 1) ? (R >> 1) : (R >> 1) - 1;        // plane B (rows 2pr+1,2pr+2)
            H[(PB + prB * S1 + C) * 2 + ((R & 1) ^ 1)] = hv;
        }
    }
    __syncthreads();

    const int h  = l >> 1;          // output row e, 0..31
    const int wh = l & 1;

    // ---- phase 2: conv1 (32x7 SAME), kh-paired dot2, filters from LDS (broadcast) ----
    float a0[8], a1[8];
    {
        #pragma unroll
        for (int w = 0; w < 8; ++w) { a0[w] = 0.f; a1[w] = 0.f; }
        const unsigned int* plane = lds + ((h & 1) ? PB : 0);
        const int pr0 = h >> 1;
        const int wb  = wh * 8;
        #pragma unroll 2
        for (int j = 0; j < 16; ++j) {           // kh pair (2j, 2j+1)
            const uint4* rp = (const uint4*)(plane + (pr0 + j) * S1 + wb);
            uint4 q0 = rp[0], q1 = rp[1], q2 = rp[2], q3 = rp[3];
            const uint4* fp4 = (const uint4*)(lds + F1B + j * 16);
            uint4 fA = fp4[0], fB = fp4[1], fC = fp4[2];
            uint2 fD = *(const uint2*)(lds + F1B + j * 16 + 12);
            unsigned int win[16] = {q0.x,q0.y,q0.z,q0.w, q1.x,q1.y,q1.z,q1.w,
                                    q2.x,q2.y,q2.z,q2.w, q3.x,q3.y,q3.z,q3.w};
            unsigned int fv[14] = {fA.x,fA.y,fA.z,fA.w, fB.x,fB.y,fB.z,fB.w,
                                   fC.x,fC.y,fC.z,fC.w, fD.x,fD.y};
            #pragma unroll
            for (int kw = 0; kw < 7; ++kw) {
                h2 f0 = u2h(fv[kw * 2 + 0]);
                h2 f1h = u2h(fv[kw * 2 + 1]);
                #pragma unroll
                for (int w = 0; w < 8; ++w) {
                    h2 wv = u2h(win[w + kw]);
                    a0[w] = FDOT2(wv, f0, a0[w]);
                    a1[w] = FDOT2(wv, f1h, a1[w]);
                }
            }
        }
    }
    __syncthreads();

    // ---- phase 3: re-zero conv2 plane region (63 rows x S2 dwords) ----
    #pragma unroll
    for (int i = 0; i < 5; ++i) {
        int n = i * 64 + l;
        if (n < (63 * S2) / 4) ((float4*)lds)[n] = z4;
    }
    __syncthreads();

    // ---- phase 4: pool1 top-8 of 16 -> conv2 plane, i-channels packed per dword ----
    {
        float own[8], recv[8];
        #pragma unroll
        for (int i = 0; i < 8; ++i) {
            own[i]  = wh ? a1[i] : a0[i];
            recv[i] = __shfl_xor(wh ? a0[i] : a1[i], 1, 64);
        }
        float v[16];
        #pragma unroll
        for (int i = 0; i < 8; ++i) {
            v[i]     = wh ? recv[i] : own[i];
            v[8 + i] = wh ? own[i] : recv[i];
        }
        int r[16];
        #pragma unroll
        for (int i = 0; i < 16; ++i) r[i] = 0;
        #pragma unroll
        for (int i = 0; i < 16; ++i)
            #pragma unroll
            for (int j = i + 1; j < 16; ++j) {
                bool ge = v[i] >= v[j];          // tie -> earlier index wins
                r[j] += ge ? 1 : 0;
                r[i] += ge ? 0 : 1;
            }
        _Float16* H = (_Float16*)lds;
        #pragma unroll
        for (int i = 0; i < 16; ++i)
            if (r[i] < 8)
                H[((h + 15) * S2 + (r[i] + 2)) * 2 + wh] = (_Float16)v[i];
    }
    __syncthreads();

    // ---- phase 5: conv2 (32x5x2 SAME), i-paired dot2, filters from LDS ----
    float c0[4], c1[4];
    {
        #pragma unroll
        for (int w = 0; w < 4; ++w) { c0[w] = 0.f; c1[w] = 0.f; }
        const int wb2 = wh * 4;
        #pragma unroll 2
        for (int kh = 0; kh < 32; ++kh) {
            const uint4* rp = (const uint4*)(lds + (h + kh) * S2 + wb2);
            uint4 qa = rp[0], qb = rp[1];
            const uint4* gp4 = (const uint4*)(lds + F2B + kh * 12);
            uint4 gA = gp4[0], gB = gp4[1];
            uint2 gD = *(const uint2*)(lds + F2B + kh * 12 + 8);
            unsigned int q[8] = {qa.x,qa.y,qa.z,qa.w, qb.x,qb.y,qb.z,qb.w};
            unsigned int gv[10] = {gA.x,gA.y,gA.z,gA.w, gB.x,gB.y,gB.z,gB.w, gD.x,gD.y};
            #pragma unroll
            for (int kw = 0; kw < 5; ++kw) {
                h2 f0 = u2h(gv[kw * 2 + 0]);
                h2 f1h = u2h(gv[kw * 2 + 1]);
                #pragma unroll
                for (int w = 0; w < 4; ++w) {
                    h2 wv = u2h(q[w + kw]);
                    c0[w] = FDOT2(wv, f0, c0[w]);
                    c1[w] = FDOT2(wv, f1h, c1[w]);
                }
            }
        }
    }

    // ---- phase 6: pool2 top-3 of 8 + tanh + dot(w1) + sigmoid ----
    {
        float own[4], recv[4];
        #pragma unroll
        for (int i = 0; i < 4; ++i) {
            own[i]  = wh ? c1[i] : c0[i];
            recv[i] = __shfl_xor(wh ? c0[i] : c1[i], 1, 64);
        }
        float v[8];
        #pragma unroll
        for (int i = 0; i < 4; ++i) {
            v[i]     = wh ? recv[i] : own[i];
            v[4 + i] = wh ? own[i] : recv[i];
        }
        int r[8];
        #pragma unroll
        for (int i = 0; i < 8; ++i) r[i] = 0;
        #pragma unroll
        for (int i = 0; i < 8; ++i)
            #pragma unroll
            for (int j = i + 1; j < 8; ++j) {
                bool ge = v[i] >= v[j];
                r[j] += ge ? 1 : 0;
                r[i] += ge ? 0 : 1;
            }
        float t0 = 0.f, t1 = 0.f, t2 = 0.f;
        #pragma unroll
        for (int i = 0; i < 8; ++i) {
            t0 = (r[i] == 0) ? v[i] : t0;
            t1 = (r[i] == 1) ? v[i] : t1;
            t2 = (r[i] == 2) ? v[i] : t2;
        }
        float s = tanhf_fast(t0) * w1[h * 6 + wh]
                + tanhf_fast(t1) * w1[h * 6 + 2 + wh]
                + tanhf_fast(t2) * w1[h * 6 + 4 + wh];
        #pragma unroll
        for (int off = 32; off; off >>= 1) s += __shfl_xor(s, off, 64);
        if (l == 0) {
            float logit = s + b1[0];
            out[b] = __builtin_amdgcn_rcpf(1.f + __expf(-logit));
        }
    }
}

extern "C" void kernel_launch(void* const* d_in, const int* in_sizes, int n_in,
                              void* d_out, int out_size, void* d_ws, size_t ws_size,
                              hipStream_t stream) {
    const int*   idx = (const int*)d_in[0];
    const float* w0  = (const float*)d_in[1];
    const float* b0  = (const float*)d_in[2];
    const float* f1  = (const float*)d_in[3];
    const float* f2  = (const float*)d_in[4];
    const float* w1  = (const float*)d_in[5];
    const float* b1  = (const float*)d_in[6];
    float* out = (float*)d_out;
    unsigned int* ws = (unsigned int*)d_ws;

    pack_filters<<<1, 256, 0, stream>>>(f1, f2, ws);
    ccpm_fwd<<<out_size, 64, 0, stream>>>(idx, w0, b0, w1, b1, ws, out);
}